// Round 15
// baseline (253825.732 us; speedup 1.0000x reference)
//
#include <hip/hip_runtime.h>
#include <math.h>

// ControlledNODE: sequential RK4 scan, T=65536 steps.
// Round-15 = r12 (best validated: 222k us, 2 full barriers/stage, 4 waves,
// 136 weight floats/lane -> VGPR 96) with two chain-shortening deltas that
// leave the sync structure byte-for-byte identical:
//  * xbuf DELETED: after BARRIER-B every lane holds xm (RK computed
//    redundantly; lanes 0..31 of each wave hold x_0..x_31). L1 broadcasts
//    x via v_readlane (literal lane index -> SGPR) feeding scalar v_fma
//    (1 sgpr src allowed) -- removes one LDS write->read round-trip and a
//    wave-barrier from the per-stage critical path.
//  * pdrift -> paired float2 pd2[32] (r8-validated): post-BARRIER-B read
//    is one b64 instead of two dependent b32s.
// Everything else (wave mapping, L1/L2/L3 split, pex exchange, barriers)
// is exactly r12.

constexpr int T_STEPS = 65536;
constexpr int HD  = 32;   // state dim
constexpr int HID = 128;  // hidden dim

typedef float v2f __attribute__((ext_vector_type(2)));

__device__ __forceinline__ v2f fma2(v2f a, v2f b, v2f c) {
    return __builtin_elementwise_fma(a, b, c);   // -> v_pk_fma_f32
}

__device__ __forceinline__ float silu_f(float a) {
    // a * sigmoid(a); exp overflow -> inf -> a/inf = 0 (correct limit)
    return a / (1.0f + __expf(-a));
}

// Broadcast lane i's value to all lanes via v_readlane (returns SGPR).
__device__ __forceinline__ float rdlane(float v, int i) {
    union { float f; int s; } u;
    u.f = v;
    u.s = __builtin_amdgcn_readlane(u.s, i);
    return u.f;
}

// Workgroup barrier without vmcnt drain.
__device__ __forceinline__ void wg_barrier() {
    asm volatile("s_waitcnt lgkmcnt(0)" ::: "memory");
    __builtin_amdgcn_s_barrier();
    asm volatile("" ::: "memory");
}

__global__ __launch_bounds__(256, 1)
void node_scan(const float* __restrict__ U,
               const float* __restrict__ h0,
               const float* __restrict__ W1, const float* __restrict__ b1,
               const float* __restrict__ W2, const float* __restrict__ b2,
               const float* __restrict__ W3, const float* __restrict__ b3,
               const float* __restrict__ Wd, const float* __restrict__ bd,
               const float* __restrict__ Wt, const float* __restrict__ bt,
               const float* __restrict__ Wc, const float* __restrict__ bc,
               float* __restrict__ out)
{
    const int tid = threadIdx.x;    // 0..255
    const int lam = tid & 63;       // lane within wave
    const int w   = tid >> 6;       // wave 0..3
    const int wk  = w & 1;          // z1 half produced == L2 K-half
    const int wo  = w >> 1;         // L2/L3 output half
    const int j1  = lam + wk * 64;  // L1 output unit
    const int o   = lam + wo * 64;  // L2 output unit
    const int m   = lam & 31;       // state/drift index
    const int sub = lam >> 5;       // L3 sub-split within wave

    __shared__ __align__(16) float  z1buf[HID];   // unit order
    __shared__ __align__(16) float  z2buf[HID];   // unit order
    __shared__ __align__(16) float  pex[2 * HID]; // L2 K-half partials
    __shared__ __align__(16) float2 pd2[32];      // L3 half partials, paired

    // ---- one-time: weights into registers ----
    float w1r[32];                                // x-part, scalar (readlane path)
#pragma unroll
    for (int i = 0; i < 32; ++i) w1r[i] = W1[i * HID + j1];
    float w1u[8];                                 // u-part
#pragma unroll
    for (int i = 0; i < 8; ++i) w1u[i] = W1[(32 + i) * HID + j1];
    const float b1r = b1[j1];

    // W2 column o over K-half [wk*64, wk*64+64), packed pairs
    v2f w2p[32];
#pragma unroll
    for (int kp = 0; kp < 32; ++kp) {
        const int k = wk * 64 + 2 * kp;
        w2p[kp].x = W2[k * HID + o];
        w2p[kp].y = W2[(k + 1) * HID + o];
    }
    const float b2r = b2[o];

    // W3: drift[m] partial over z2 units [wo*64 + sub*32, +32), packed pairs
    v2f w3p[16];
#pragma unroll
    for (int i = 0; i < 16; ++i) {
        const int u0 = wo * 64 + sub * 32 + 2 * i;
        w3p[i].x = W3[u0 * HD + m];
        w3p[i].y = W3[(u0 + 1) * HD + m];
    }
    const float b3r = b3[m];

    // heads: wave0 -> d, wave1 -> t, wave2 -> c, wave3 idle
    const float whr = (w == 0) ? Wd[m] : (w == 1) ? Wt[m] : (w == 2) ? Wc[m] : 0.0f;
    const float bh  = (w == 0) ? bd[0] : (w == 1) ? bt[0] : (w == 2) ? bc[0] : 0.0f;

    float hm   = h0[m];    // replicated in all 256 lanes
    float xm   = hm;       // current stage input state x[m]
    float kacc = 0.0f;

    const float DT  = 5.0f / 60.0f;
    const float HDT = 0.5f * DT;
    const float W6  = DT / 6.0f;

    // u double-buffer (same addr all lanes -> broadcast, L2-cached)
    float4 ua = *(const float4*)(U);
    float4 ub = *(const float4*)(U + 4);

    wg_barrier();

    for (int t = 0; t < T_STEPS; ++t) {
        // prefetch next step's u (no vmcnt drain at barriers -> in flight)
        const int tn = (t + 1 < T_STEPS) ? (t + 1) : t;
        const float4 na = *(const float4*)(U + tn * 8);
        const float4 nb = *(const float4*)(U + tn * 8 + 4);

        // ---- heads from current h (pre-update): one head per wave ----
        {
            float p = hm * whr;
            p += __shfl_xor(p, 16);
            p += __shfl_xor(p, 8);
            p += __shfl_xor(p, 4);
            p += __shfl_xor(p, 2);
            p += __shfl_xor(p, 1);
            if (lam == 0 && w < 3) out[w * T_STEPS + t] = p + bh;
        }

        // ---- u-projection: constant across the 4 RK stages, hoisted ----
        float upj = b1r;
        upj = fmaf(ua.x, w1u[0], upj);
        upj = fmaf(ua.y, w1u[1], upj);
        upj = fmaf(ua.z, w1u[2], upj);
        upj = fmaf(ua.w, w1u[3], upj);
        upj = fmaf(ub.x, w1u[4], upj);
        upj = fmaf(ub.y, w1u[5], upj);
        upj = fmaf(ub.z, w1u[6], upj);
        upj = fmaf(ub.w, w1u[7], upj);

#pragma unroll
        for (int st = 0; st < 4; ++st) {
            // ---- L1: z1[j1] = silu(x @ W1x + up), x via readlane bcast ----
            float a0 = upj, a1 = 0.0f, a2 = 0.0f, a3 = 0.0f;
#pragma unroll
            for (int i = 0; i < 32; i += 4) {
                a0 = fmaf(rdlane(xm, i + 0), w1r[i + 0], a0);
                a1 = fmaf(rdlane(xm, i + 1), w1r[i + 1], a1);
                a2 = fmaf(rdlane(xm, i + 2), w1r[i + 2], a2);
                a3 = fmaf(rdlane(xm, i + 3), w1r[i + 3], a3);
            }
            z1buf[j1] = silu_f((a0 + a1) + (a2 + a3));   // waves (0,2) h0, (1,3) h1
            __builtin_amdgcn_wave_barrier();             // own z1 half < own reads

            // ---- L2: output o over own K-half [wk*64, +64) ----
            v2f c0 = {0.0f, 0.0f}, c1 = {0.0f, 0.0f};
            const float4* z1v = (const float4*)(z1buf + wk * 64);
#pragma unroll
            for (int i4 = 0; i4 < 16; ++i4) {
                const float4 v = z1v[i4];           // broadcast read (own half)
                v2f lo; lo.x = v.x; lo.y = v.y;
                v2f hi; hi.x = v.z; hi.y = v.w;
                c0 = fma2(lo, w2p[2 * i4],     c0);
                c1 = fma2(hi, w2p[2 * i4 + 1], c1);
            }
            const v2f cs = c0 + c1;
            const float mine = cs.x + cs.y;         // K-half partial for unit o
            pex[wk * HID + o] = mine;
            wg_barrier();                            // BARRIER-A: pex exchange

            const float po = pex[(1 ^ wk) * HID + o];
            const float z2 = silu_f(mine + po + b2r);
            z2buf[o] = z2;                           // waves (0,1) h0, (2,3) h1
            __builtin_amdgcn_wave_barrier();         // own z2 half < own reads

            // ---- L3 partial: drift[m] over own z2 half, sub-split ----
            v2f p0 = {0.0f, 0.0f}, p1 = {0.0f, 0.0f};
            const float4* z2v = (const float4*)(z2buf + wo * 64 + sub * 32);
#pragma unroll
            for (int i4 = 0; i4 < 8; ++i4) {
                const float4 v = z2v[i4];           // 2 addr groups: free
                v2f lo; lo.x = v.x; lo.y = v.y;
                v2f hi; hi.x = v.z; hi.y = v.w;
                p0 = fma2(lo, w3p[2 * i4],     p0);
                p1 = fma2(hi, w3p[2 * i4 + 1], p1);
            }
            const v2f ps = p0 + p1;
            float pr = ps.x + ps.y;
            pr += __shfl_xor(pr, 32);               // combine sub halves in-wave
            ((float*)&pd2[m])[wo] = pr;             // component wo; dup lanes same
            wg_barrier();                            // BARRIER-B: drift exchange

            // ---- RK combine: ALL lanes redundantly (hm replicated) ----
            {
                const float2 pp = pd2[m];            // one b64 read
                const float drift = (pp.x + pp.y) + b3r;
                const float k = 0.02f * drift - 0.1f * xm;
                if (st == 0)      { kacc = k;           xm = hm + HDT * k; }
                else if (st == 1) { kacc += 2.0f * k;   xm = hm + HDT * k; }
                else if (st == 2) { kacc += 2.0f * k;   xm = hm + DT  * k; }
                else {
                    kacc += k;
                    float hn = hm + W6 * kacc;
                    if (!isfinite(hn)) hn = 0.0f;        // nan_to_num BEFORE tanh
                    hn = tanhf(hn);
                    hn = fminf(fmaxf(hn, -5.0f), 5.0f);  // fidelity no-op after tanh
                    hm = hn; xm = hn;
                }
            }
            // xm now live in registers of every lane; L1 readlane-bcasts it.
        }
        ua = na; ub = nb;
    }

    if (tid < HD) out[3 * T_STEPS + tid] = hm;
}

extern "C" void kernel_launch(void* const* d_in, const int* in_sizes, int n_in,
                              void* d_out, int out_size, void* d_ws, size_t ws_size,
                              hipStream_t stream) {
    const float* U  = (const float*)d_in[0];
    const float* h0 = (const float*)d_in[1];
    const float* W1 = (const float*)d_in[2];
    const float* b1 = (const float*)d_in[3];
    const float* W2 = (const float*)d_in[4];
    const float* b2 = (const float*)d_in[5];
    const float* W3 = (const float*)d_in[6];
    const float* b3 = (const float*)d_in[7];
    const float* Wd = (const float*)d_in[8];
    const float* bd = (const float*)d_in[9];
    const float* Wt = (const float*)d_in[10];
    const float* bt = (const float*)d_in[11];
    const float* Wc = (const float*)d_in[12];
    const float* bc = (const float*)d_in[13];
    float* out = (float*)d_out;

    node_scan<<<1, 256, 0, stream>>>(U, h0, W1, b1, W2, b2, W3, b3,
                                     Wd, bd, Wt, bt, Wc, bc, out);
}

// Round 16
// 221522.900 us; speedup vs baseline: 1.1458x; 1.1458x over previous
//
#include <hip/hip_runtime.h>
#include <math.h>

// ControlledNODE: sequential RK4 scan, T=65536 steps.
// FINAL (round-16) = round-12 verbatim: the best validated kernel (222k us,
// 2.11x vs session baseline). 256 threads = 4 waves (1/SIMD); per-lane
// weights 136 floats (W1 40 + W2 64 + W3 32) -> fully arch-VGPR-resident
// (VGPR 96, no AGPR parking). Two full barriers per RK stage (pex exchange
// + pdrift exchange) -- proven race-free under the replay tripwire; the
// one-barrier variant (r13) races, and both round-trip-elimination variants
// (r14 full-K L3, r15 readlane broadcast) measured net-negative.
// Wave w = (wk = w&1: z1-half produced = L2 K-half; wo = w>>1: output half).
// All other LDS producer->consumer edges are wave-local in-order DS.

constexpr int T_STEPS = 65536;
constexpr int HD  = 32;   // state dim
constexpr int HID = 128;  // hidden dim

typedef float v2f __attribute__((ext_vector_type(2)));

__device__ __forceinline__ v2f fma2(v2f a, v2f b, v2f c) {
    return __builtin_elementwise_fma(a, b, c);   // -> v_pk_fma_f32
}

__device__ __forceinline__ float silu_f(float a) {
    // a * sigmoid(a); exp overflow -> inf -> a/inf = 0 (correct limit)
    return a / (1.0f + __expf(-a));
}

// Workgroup barrier without vmcnt drain.
__device__ __forceinline__ void wg_barrier() {
    asm volatile("s_waitcnt lgkmcnt(0)" ::: "memory");
    __builtin_amdgcn_s_barrier();
    asm volatile("" ::: "memory");
}

__global__ __launch_bounds__(256, 1)
void node_scan(const float* __restrict__ U,
               const float* __restrict__ h0,
               const float* __restrict__ W1, const float* __restrict__ b1,
               const float* __restrict__ W2, const float* __restrict__ b2,
               const float* __restrict__ W3, const float* __restrict__ b3,
               const float* __restrict__ Wd, const float* __restrict__ bd,
               const float* __restrict__ Wt, const float* __restrict__ bt,
               const float* __restrict__ Wc, const float* __restrict__ bc,
               float* __restrict__ out)
{
    const int tid = threadIdx.x;    // 0..255
    const int lam = tid & 63;       // lane within wave
    const int w   = tid >> 6;       // wave 0..3
    const int wk  = w & 1;          // z1 half produced == L2 K-half
    const int wo  = w >> 1;         // L2/L3 output half
    const int j1  = lam + wk * 64;  // L1 output unit
    const int o   = lam + wo * 64;  // L2 output unit
    const int m   = tid & 31;       // state/drift index
    const int sub = (tid >> 5) & 1; // L3 sub-split within wave

    __shared__ __align__(16) float xbuf[HD];      // RK-stage state input
    __shared__ __align__(16) float z1buf[HID];    // unit order
    __shared__ __align__(16) float z2buf[HID];    // unit order
    __shared__ __align__(16) float pex[2 * HID];  // L2 K-half partials
    __shared__ __align__(16) float pdrift[64];    // L3 half partials

    // ---- one-time: weights into registers as packed pairs ----
    v2f w1p[20];                                  // rows 0..31 = x, 32..39 = u
#pragma unroll
    for (int i = 0; i < 20; ++i) {
        w1p[i].x = W1[(2 * i) * HID + j1];
        w1p[i].y = W1[(2 * i + 1) * HID + j1];
    }
    const float b1r = b1[j1];

    // W2 column o over K-half [wk*64, wk*64+64)
    v2f w2p[32];
#pragma unroll
    for (int kp = 0; kp < 32; ++kp) {
        const int k = wk * 64 + 2 * kp;
        w2p[kp].x = W2[k * HID + o];
        w2p[kp].y = W2[(k + 1) * HID + o];
    }
    const float b2r = b2[o];

    // W3: drift[m] partial over z2 units [wo*64 + sub*32, +32)
    v2f w3p[16];
#pragma unroll
    for (int i = 0; i < 16; ++i) {
        const int u0 = wo * 64 + sub * 32 + 2 * i;
        w3p[i].x = W3[u0 * HD + m];
        w3p[i].y = W3[(u0 + 1) * HD + m];
    }
    const float b3r = b3[m];

    // heads: wave0 -> d, wave1 -> t, wave2 -> c, wave3 idle
    const float whr = (w == 0) ? Wd[m] : (w == 1) ? Wt[m] : (w == 2) ? Wc[m] : 0.0f;
    const float bh  = (w == 0) ? bd[0] : (w == 1) ? bt[0] : (w == 2) ? bc[0] : 0.0f;

    float hm   = h0[m];    // replicated in all 256 lanes
    float xm   = hm;       // current stage input state x[m]
    float kacc = 0.0f;

    const float DT  = 5.0f / 60.0f;
    const float HDT = 0.5f * DT;
    const float W6  = DT / 6.0f;

    // u double-buffer (same addr all lanes -> broadcast, L2-cached)
    float4 ua = *(const float4*)(U);
    float4 ub = *(const float4*)(U + 4);

    xbuf[m] = xm;                    // all lanes, identical values: benign
    wg_barrier();

    for (int t = 0; t < T_STEPS; ++t) {
        // prefetch next step's u (no vmcnt drain at barriers -> in flight)
        const int tn = (t + 1 < T_STEPS) ? (t + 1) : t;
        const float4 na = *(const float4*)(U + tn * 8);
        const float4 nb = *(const float4*)(U + tn * 8 + 4);

        // ---- heads from current h (pre-update): one head per wave ----
        {
            float p = hm * whr;
            p += __shfl_xor(p, 16);
            p += __shfl_xor(p, 8);
            p += __shfl_xor(p, 4);
            p += __shfl_xor(p, 2);
            p += __shfl_xor(p, 1);
            if (lam == 0 && w < 3) out[w * T_STEPS + t] = p + bh;
        }

        // ---- u-projection: constant across the 4 RK stages, hoisted ----
        float upj;
        {
            v2f u0; u0.x = ua.x; u0.y = ua.y;
            v2f u1; u1.x = ua.z; u1.y = ua.w;
            v2f u2; u2.x = ub.x; u2.y = ub.y;
            v2f u3; u3.x = ub.z; u3.y = ub.w;
            v2f up = {b1r, 0.0f};
            up = fma2(u0, w1p[16], up);
            up = fma2(u1, w1p[17], up);
            up = fma2(u2, w1p[18], up);
            up = fma2(u3, w1p[19], up);
            upj = up.x + up.y;
        }

#pragma unroll
        for (int st = 0; st < 4; ++st) {
            // ---- L1: z1[j1] = silu([x,u] @ W1 + b1) (replicated x2) ----
            v2f a0 = {upj, 0.0f}, a1 = {0.0f, 0.0f};
            const float4* xv = (const float4*)xbuf;
#pragma unroll
            for (int i4 = 0; i4 < 8; ++i4) {
                const float4 v = xv[i4];            // broadcast read (own writes)
                v2f lo; lo.x = v.x; lo.y = v.y;
                v2f hi; hi.x = v.z; hi.y = v.w;
                a0 = fma2(lo, w1p[2 * i4],     a0);
                a1 = fma2(hi, w1p[2 * i4 + 1], a1);
            }
            const v2f as = a0 + a1;
            z1buf[j1] = silu_f(as.x + as.y);        // waves (0,2) half0, (1,3) half1
            __builtin_amdgcn_wave_barrier();         // own z1 half < own reads

            // ---- L2: output o over own K-half [wk*64, +64) ----
            v2f c0 = {0.0f, 0.0f}, c1 = {0.0f, 0.0f};
            const float4* z1v = (const float4*)(z1buf + wk * 64);
#pragma unroll
            for (int i4 = 0; i4 < 16; ++i4) {
                const float4 v = z1v[i4];           // broadcast read (own half)
                v2f lo; lo.x = v.x; lo.y = v.y;
                v2f hi; hi.x = v.z; hi.y = v.w;
                c0 = fma2(lo, w2p[2 * i4],     c0);
                c1 = fma2(hi, w2p[2 * i4 + 1], c1);
            }
            const v2f cs = c0 + c1;
            const float mine = cs.x + cs.y;         // K-half partial for unit o
            pex[wk * HID + o] = mine;
            wg_barrier();                            // BARRIER-A: pex exchange

            const float po = pex[(1 ^ wk) * HID + o];
            const float z2 = silu_f(mine + po + b2r);
            z2buf[o] = z2;                           // waves (0,1) half0, (2,3) half1
            __builtin_amdgcn_wave_barrier();         // own z2 half < own reads

            // ---- L3 partial: drift[m] over own z2 half, sub-split ----
            v2f p0 = {0.0f, 0.0f}, p1 = {0.0f, 0.0f};
            const float4* z2v = (const float4*)(z2buf + wo * 64 + sub * 32);
#pragma unroll
            for (int i4 = 0; i4 < 8; ++i4) {
                const float4 v = z2v[i4];           // 2 addr groups: free
                v2f lo; lo.x = v.x; lo.y = v.y;
                v2f hi; hi.x = v.z; hi.y = v.w;
                p0 = fma2(lo, w3p[2 * i4],     p0);
                p1 = fma2(hi, w3p[2 * i4 + 1], p1);
            }
            const v2f ps = p0 + p1;
            float pr = ps.x + ps.y;
            pr += __shfl_xor(pr, 32);   // combine sub halves within wave
            pdrift[wo * 32 + m] = pr;   // 2 waves/half identical: benign
            wg_barrier();                            // BARRIER-B: drift exchange

            // ---- RK combine: ALL lanes redundantly (hm replicated) ----
            {
                const float drift = (pdrift[m] + pdrift[m + 32]) + b3r;
                const float k = 0.02f * drift - 0.1f * xm;
                if (st == 0)      { kacc = k;           xm = hm + HDT * k; }
                else if (st == 1) { kacc += 2.0f * k;   xm = hm + HDT * k; }
                else if (st == 2) { kacc += 2.0f * k;   xm = hm + DT  * k; }
                else {
                    kacc += k;
                    float hn = hm + W6 * kacc;
                    if (!isfinite(hn)) hn = 0.0f;        // nan_to_num BEFORE tanh
                    hn = tanhf(hn);
                    hn = fminf(fmaxf(hn, -5.0f), 5.0f);  // fidelity no-op after tanh
                    hm = hn; xm = hn;
                }
                xbuf[m] = xm;   // all lanes, identical values: benign race
            }
            __builtin_amdgcn_wave_barrier();         // wave-local: xbuf -> L1
        }
        ua = na; ub = nb;
    }

    if (tid < HD) out[3 * T_STEPS + tid] = hm;
}

extern "C" void kernel_launch(void* const* d_in, const int* in_sizes, int n_in,
                              void* d_out, int out_size, void* d_ws, size_t ws_size,
                              hipStream_t stream) {
    const float* U  = (const float*)d_in[0];
    const float* h0 = (const float*)d_in[1];
    const float* W1 = (const float*)d_in[2];
    const float* b1 = (const float*)d_in[3];
    const float* W2 = (const float*)d_in[4];
    const float* b2 = (const float*)d_in[5];
    const float* W3 = (const float*)d_in[6];
    const float* b3 = (const float*)d_in[7];
    const float* Wd = (const float*)d_in[8];
    const float* bd = (const float*)d_in[9];
    const float* Wt = (const float*)d_in[10];
    const float* bt = (const float*)d_in[11];
    const float* Wc = (const float*)d_in[12];
    const float* bc = (const float*)d_in[13];
    float* out = (float*)d_out;

    node_scan<<<1, 256, 0, stream>>>(U, h0, W1, b1, W2, b2, W3, b3,
                                     Wd, bd, Wt, bt, Wc, bc, out);
}